// Round 2
// baseline (282.641 us; speedup 1.0000x reference)
//
#include <hip/hip_runtime.h>
#include <stdint.h>

// Problem constants: B=8, N=1024, IN_F=1024, E=256, H=4, A=64
typedef __attribute__((ext_vector_type(8))) short short8;
typedef __attribute__((ext_vector_type(4))) float f32x4;

__device__ __forceinline__ float b2f(unsigned short u) {
    union { unsigned int i; float f; } v; v.i = ((unsigned int)u) << 16; return v.f;
}
__device__ __forceinline__ unsigned short f2b(float f) {
    union { float f; unsigned int i; } v; v.f = f;
    unsigned int u = v.i;
    u = (u + 0x7FFFu + ((u >> 16) & 1u)) >> 16;
    return (unsigned short)u;
}
__device__ __forceinline__ void glds16(const void* g, const void* l) {
    __builtin_amdgcn_global_load_lds(
        (const __attribute__((address_space(1))) unsigned int*)g,
        (__attribute__((address_space(3))) unsigned int*)l, 16, 0, 0);
}

// Detect input dtype: bf16-packed (flag=1) vs float32 (flag=0).
// For bf16 pairs, bits 14..7 of each u32 are a bf16 exponent (~[107,128] for
// N(0,1) data); for fp32 they are uniform mantissa bits (P(in range)=0.16).
__global__ void detect_kern(const unsigned int* __restrict__ x, int* __restrict__ flag) {
    int tid = threadIdx.x;            // one wave (64 threads)
    unsigned int w = x[tid];
    unsigned int e = (w >> 7) & 0xFF;
    int isbf = (e >= 100 && e <= 140) ? 1 : 0;
    unsigned long long m = __ballot(isbf);
    if (tid == 0) flag[0] = (__popcll(m) >= 48) ? 1 : 0;
}

// Convert 8 elements/thread from (fp32 | bf16) to bf16.
__global__ void conv8(const void* __restrict__ in, unsigned short* __restrict__ out,
                      const int* __restrict__ flag, int total8) {
    int i = blockIdx.x * 256 + threadIdx.x;
    if (i >= total8) return;
    ushort4 o0, o1;
    if (*flag) {
        const ushort4* p = (const ushort4*)in + (size_t)i * 2;
        o0 = p[0]; o1 = p[1];
    } else {
        const float4* p = (const float4*)in + (size_t)i * 2;
        float4 a = p[0], b = p[1];
        o0.x = f2b(a.x); o0.y = f2b(a.y); o0.z = f2b(a.z); o0.w = f2b(a.w);
        o1.x = f2b(b.x); o1.y = f2b(b.y); o1.z = f2b(b.z); o1.w = f2b(b.w);
    }
    ((ushort4*)out)[(size_t)i * 2]     = o0;
    ((ushort4*)out)[(size_t)i * 2 + 1] = o1;
}

// Batched transpose + dtype convert: in[bt][r][c] -> out[bt][c][r], R=1024, C=2^log2C
__global__ void t_kern(const void* __restrict__ in, unsigned short* __restrict__ out,
                       const int* __restrict__ flag, int log2C, int total) {
    int id = blockIdx.x * 256 + threadIdx.x;
    if (id >= total) return;
    unsigned short v;
    if (*flag) v = ((const unsigned short*)in)[id];
    else       v = f2b(((const float*)in)[id]);
    int c  = id & ((1 << log2C) - 1);
    int r  = (id >> log2C) & 1023;
    int bt = id >> (log2C + 10);
    out[(bt << (log2C + 10)) + (c << 10) + r] = v;
}

// K1: Wh = x @ W[h]  (M=8192, N=1024=H*E, K=1024), writes WhT[hb][e][m] bf16.
// 128x128 tile, BK=32, 4 waves in 2x2, frag-ordered LDS via global_load_lds.
__global__ __launch_bounds__(256) void k1_gemm(
        const unsigned short* __restrict__ x,
        const unsigned short* __restrict__ WT,      // [H][E=256][K=1024]
        unsigned short* __restrict__ WhT) {         // [H*8+b][256][1024]
    __shared__ unsigned short smA[8 * 512];
    __shared__ unsigned short smB[8 * 512];
    int tid = threadIdx.x;
    int w = tid >> 6, lane = tid & 63;
    int lr = lane & 15, lq = lane >> 4;
    int col0 = blockIdx.x * 128;
    int row0 = blockIdx.y * 128;
    int h = col0 >> 8;
    int e_base = col0 & 255;
    int b = row0 >> 10;
    int m_base = row0 & 1023;
    int wr = w >> 1, wc = w & 1;

    f32x4 acc[4][4] = {};

    for (int k0 = 0; k0 < 1024; k0 += 32) {
        __syncthreads();
#pragma unroll
        for (int s = 0; s < 2; s++) {
            int g = 2 * w + s;   // 0..7 across 4 waves
            const unsigned short* srcA =
                x + (size_t)(row0 + g * 16 + lr) * 1024 + k0 + lq * 8;
            glds16(srcA, &smA[g * 512]);
            const unsigned short* srcB =
                WT + (size_t)(h * 256 + e_base + g * 16 + lr) * 1024 + k0 + lq * 8;
            glds16(srcB, &smB[g * 512]);
        }
        __syncthreads();
        short8 af[4], bf[4];
#pragma unroll
        for (int i = 0; i < 4; i++)
            af[i] = *(const short8*)&smA[(wr * 4 + i) * 512 + lane * 8];
#pragma unroll
        for (int j = 0; j < 4; j++)
            bf[j] = *(const short8*)&smB[(wc * 4 + j) * 512 + lane * 8];
#pragma unroll
        for (int i = 0; i < 4; i++)
#pragma unroll
            for (int j = 0; j < 4; j++)
                acc[i][j] = __builtin_amdgcn_mfma_f32_16x16x32_bf16(
                    af[i], bf[j], acc[i][j], 0, 0, 0);
    }

    // Transposed epilogue: lane holds fixed e = col, 4 consecutive m (regs)
    int hb = h * 8 + b;
#pragma unroll
    for (int i = 0; i < 4; i++) {
#pragma unroll
        for (int j = 0; j < 4; j++) {
            int e = e_base + (wc * 4 + j) * 16 + lr;
            int m = m_base + (wr * 4 + i) * 16 + lq * 4;
            ushort4 vs;
            vs.x = f2b(acc[i][j][0]);
            vs.y = f2b(acc[i][j][1]);
            vs.z = f2b(acc[i][j][2]);
            vs.w = f2b(acc[i][j][3]);
            *(ushort4*)&WhT[(size_t)(hb * 256 + e) * 1024 + m] = vs;
        }
    }
}

// K1b: f1[hb][n] = sum_e WhT[hb][e][n]*a1[h][e]; f2 likewise. Coalesced over n.
__global__ void k1b_f12(const unsigned short* __restrict__ WhT,
                        const unsigned short* __restrict__ a1,
                        const unsigned short* __restrict__ a2,
                        float* __restrict__ f1, float* __restrict__ f2) {
    int hb = blockIdx.y;
    int n = blockIdx.x * 256 + threadIdx.x;
    int h = hb >> 3;
    float s1 = 0.f, s2 = 0.f;
    for (int e = 0; e < 256; e++) {
        float wv = b2f(WhT[(size_t)(hb * 256 + e) * 1024 + n]);
        s1 += wv * b2f(a1[h * 256 + e]);
        s2 += wv * b2f(a2[h * 256 + e]);
    }
    f1[hb * 1024 + n] = s1;
    f2[hb * 1024 + n] = s2;
}

// K2: masked-softmax attention + P@Wh + ELU -> feat[bn][h*256+e] bf16.
// Block: (hb, 64-row n-tile), 8 waves: wave=(row-group g 0..3, e-half eh 0..1).
// Single pass: p = exp(leakyrelu(f1+f2))*mask (logits small; no max-sub needed).
__global__ __launch_bounds__(512) void k2_attn(
        const unsigned short* __restrict__ WhT,
        const int* __restrict__ adj,
        const float* __restrict__ f1, const float* __restrict__ f2,
        unsigned short* __restrict__ feat) {
    __shared__ unsigned short smW[16 * 512];
    int tid = threadIdx.x;
    int w = tid >> 6, lane = tid & 63;
    int lr = lane & 15, lq = lane >> 4;
    int g = w & 3, eh = w >> 2;
    int n0 = blockIdx.x * 64;
    int hb = blockIdx.y;
    int h = hb >> 3, b = hb & 7;
    int n = n0 + g * 16 + lr;
    float f1n = f1[hb * 1024 + n];
    const unsigned short* whbase = WhT + (size_t)hb * 256 * 1024;

    f32x4 acc[8] = {};
    float den = 0.f;

    for (int m0 = 0; m0 < 1024; m0 += 32) {
        __syncthreads();
#pragma unroll
        for (int s = 0; s < 2; s++) {
            int t = 2 * w + s;   // 16 e-tiles staged by 8 waves
            const unsigned short* src =
                whbase + (size_t)(t * 16 + lr) * 1024 + m0 + lq * 8;
            glds16(src, &smW[t * 512]);
        }
        __syncthreads();

        const int* adjp = adj + (size_t)(b * 1024 + n) * 1024 + m0 + lq * 8;
        int4 ad0 = *(const int4*)adjp;
        int4 ad1 = *(const int4*)(adjp + 4);
        const float* f2p = f2 + hb * 1024 + m0 + lq * 8;
        float4 f20 = *(const float4*)f2p;
        float4 f21 = *(const float4*)(f2p + 4);
        int   am[8] = {ad0.x, ad0.y, ad0.z, ad0.w, ad1.x, ad1.y, ad1.z, ad1.w};
        float fm[8] = {f20.x, f20.y, f20.z, f20.w, f21.x, f21.y, f21.z, f21.w};
        short8 af;
#pragma unroll
        for (int j = 0; j < 8; j++) {
            float t_ = f1n + fm[j];
            float e_ = t_ > 0.f ? t_ : 0.2f * t_;          // leaky relu
            float p  = am[j] > 0 ? __expf(e_) : 0.f;       // mask -> exactly 0
            unsigned short pb = f2b(p);
            af[j] = (short)pb;
            den += b2f(pb);          // bf16-rounded p: consistent num/denom
        }
#pragma unroll
        for (int i = 0; i < 8; i++) {
            short8 bf = *(const short8*)&smW[(eh * 8 + i) * 512 + lane * 8];
            acc[i] = __builtin_amdgcn_mfma_f32_16x16x32_bf16(af, bf, acc[i], 0, 0, 0);
        }
    }

    // den per lane covers (row lr, m-quad lq); reduce over the 4 quads
    den += __shfl_xor(den, 16, 64);
    den += __shfl_xor(den, 32, 64);

#pragma unroll
    for (int rr = 0; rr < 4; rr++) {
        float dr = __shfl(den, lq * 4 + rr, 64);   // den of C-layout row
        float rdr = 1.0f / dr;
        int nn = n0 + g * 16 + lq * 4 + rr;
#pragma unroll
        for (int i = 0; i < 8; i++) {
            int e = eh * 128 + i * 16 + lr;
            float v = acc[i][rr] * rdr;
            float o = v > 0.f ? v : __expf(v) - 1.f;   // elu
            feat[(size_t)(b * 1024 + nn) * 1024 + h * 256 + e] = f2b(o);
        }
    }
}

// K3: out = feat @ W_act + b_act  (M=8192, K=1024, N=64), out dtype per flag.
__global__ __launch_bounds__(256) void k3_out(
        const unsigned short* __restrict__ feat,
        const unsigned short* __restrict__ WactT,   // [64][1024]
        const unsigned short* __restrict__ bact,
        void* __restrict__ out, const int* __restrict__ flag) {
    __shared__ unsigned short smA[2 * 512];
    __shared__ unsigned short smB[4 * 512];
    int tid = threadIdx.x;
    int w = tid >> 6, lane = tid & 63;
    int lr = lane & 15, lq = lane >> 4;
    int row0 = blockIdx.x * 32;
    int g = w & 1, ch = w >> 1;
    int bf16out = *flag;
    f32x4 acc[2] = {};

    for (int k0 = 0; k0 < 1024; k0 += 32) {
        __syncthreads();
        if (w < 2) {
            const unsigned short* src =
                feat + (size_t)(row0 + w * 16 + lr) * 1024 + k0 + lq * 8;
            glds16(src, &smA[w * 512]);
        } else {
#pragma unroll
            for (int s = 0; s < 2; s++) {
                int t = (w - 2) * 2 + s;
                const unsigned short* src =
                    WactT + (size_t)(t * 16 + lr) * 1024 + k0 + lq * 8;
                glds16(src, &smB[t * 512]);
            }
        }
        __syncthreads();
        short8 af = *(const short8*)&smA[g * 512 + lane * 8];
#pragma unroll
        for (int j = 0; j < 2; j++) {
            short8 bf = *(const short8*)&smB[(ch * 2 + j) * 512 + lane * 8];
            acc[j] = __builtin_amdgcn_mfma_f32_16x16x32_bf16(af, bf, acc[j], 0, 0, 0);
        }
    }
#pragma unroll
    for (int j = 0; j < 2; j++) {
        int col = ch * 32 + j * 16 + lr;
        float bv = b2f(bact[col]);
#pragma unroll
        for (int rr = 0; rr < 4; rr++) {
            int r = row0 + g * 16 + lq * 4 + rr;
            float val = acc[j][rr] + bv;
            if (bf16out) ((unsigned short*)out)[(size_t)r * 64 + col] = f2b(val);
            else         ((float*)out)[(size_t)r * 64 + col] = val;
        }
    }
}

extern "C" void kernel_launch(void* const* d_in, const int* in_sizes, int n_in,
                              void* d_out, int out_size, void* d_ws, size_t ws_size,
                              hipStream_t stream) {
    const void* x    = d_in[0];
    const int*  adj  = (const int*)d_in[1];
    const void* W    = d_in[2];
    const void* a1   = d_in[3];
    const void* a2   = d_in[4];
    const void* Wact = d_in[5];
    const void* bact = d_in[6];

    char* ws = (char*)d_ws;
    // Workspace layout (~36.05 MB). xb aliases feat (xb dead before k2 writes feat).
    unsigned short* WhT   = (unsigned short*)(ws);               // 16 MB  [32][256][1024]
    unsigned short* xb    = (unsigned short*)(ws + 16777216);    // 16 MB  [8192][1024] (== feat)
    unsigned short* feat  = (unsigned short*)(ws + 16777216);    // 16 MB  [8192][1024]
    unsigned short* WT    = (unsigned short*)(ws + 33554432);    //  2 MB  [4][256][1024]
    unsigned short* WactT = (unsigned short*)(ws + 35651584);    // 128 KB [64][1024]
    float*          f1    = (float*)(ws + 35782656);             // 128 KB [32][1024]
    float*          f2    = (float*)(ws + 35913728);             // 128 KB [32][1024]
    unsigned short* a1b   = (unsigned short*)(ws + 36044800);    // 2 KB
    unsigned short* a2b   = (unsigned short*)(ws + 36046848);    // 2 KB
    unsigned short* bactb = (unsigned short*)(ws + 36048896);    // 128 B
    int*            flag  = (int*)(ws + 36049024);               // 16 B
    if (ws_size < (size_t)36049040) return;

    detect_kern<<<1, 64, 0, stream>>>((const unsigned int*)x, flag);
    conv8<<<4096, 256, 0, stream>>>(x, xb, flag, 1048576);        // 8.4M elems
    conv8<<<1, 256, 0, stream>>>(a1, a1b, flag, 128);
    conv8<<<1, 256, 0, stream>>>(a2, a2b, flag, 128);
    conv8<<<1, 256, 0, stream>>>(bact, bactb, flag, 8);
    t_kern<<<4096, 256, 0, stream>>>(W, WT, flag, 8, 1048576);
    t_kern<<<256, 256, 0, stream>>>(Wact, WactT, flag, 6, 65536);
    k1_gemm<<<dim3(8, 64), 256, 0, stream>>>(xb, WT, WhT);
    k1b_f12<<<dim3(4, 32), 256, 0, stream>>>(WhT, a1b, a2b, f1, f2);
    k2_attn<<<dim3(16, 32), 512, 0, stream>>>(WhT, adj, f1, f2, feat);
    k3_out<<<256, 256, 0, stream>>>(feat, WactT, bactb, d_out, flag);
}

// Round 3
// 256.907 us; speedup vs baseline: 1.1002x; 1.1002x over previous
//
#include <hip/hip_runtime.h>
#include <stdint.h>

// Problem constants: B=8, N=1024, IN_F=1024, E=256, H=4, A=64
typedef __attribute__((ext_vector_type(8))) short short8;
typedef __attribute__((ext_vector_type(4))) float f32x4;

__device__ __forceinline__ float b2f(unsigned short u) {
    union { unsigned int i; float f; } v; v.i = ((unsigned int)u) << 16; return v.f;
}
__device__ __forceinline__ unsigned short f2b(float f) {
    union { float f; unsigned int i; } v; v.f = f;
    unsigned int u = v.i;
    u = (u + 0x7FFFu + ((u >> 16) & 1u)) >> 16;
    return (unsigned short)u;
}
__device__ __forceinline__ void glds16(const void* g, const void* l) {
    __builtin_amdgcn_global_load_lds(
        (const __attribute__((address_space(1))) unsigned int*)g,
        (__attribute__((address_space(3))) unsigned int*)l, 16, 0, 0);
}

// Detect input dtype: bf16-packed (flag=1) vs float32 (flag=0).
__global__ void detect_kern(const unsigned int* __restrict__ x, int* __restrict__ flag) {
    int tid = threadIdx.x;            // one wave (64 threads)
    unsigned int w = x[tid];
    unsigned int e = (w >> 7) & 0xFF;
    int isbf = (e >= 100 && e <= 140) ? 1 : 0;
    unsigned long long m = __ballot(isbf);
    if (tid == 0) flag[0] = (__popcll(m) >= 48) ? 1 : 0;
}

// Convert 8 elements/thread from (fp32 | bf16) to bf16.
__global__ void conv8(const void* __restrict__ in, unsigned short* __restrict__ out,
                      const int* __restrict__ flag, int total8) {
    int i = blockIdx.x * 256 + threadIdx.x;
    if (i >= total8) return;
    ushort4 o0, o1;
    if (*flag) {
        const ushort4* p = (const ushort4*)in + (size_t)i * 2;
        o0 = p[0]; o1 = p[1];
    } else {
        const float4* p = (const float4*)in + (size_t)i * 2;
        float4 a = p[0], b = p[1];
        o0.x = f2b(a.x); o0.y = f2b(a.y); o0.z = f2b(a.z); o0.w = f2b(a.w);
        o1.x = f2b(b.x); o1.y = f2b(b.y); o1.z = f2b(b.z); o1.w = f2b(b.w);
    }
    ((ushort4*)out)[(size_t)i * 2]     = o0;
    ((ushort4*)out)[(size_t)i * 2 + 1] = o1;
}

// Batched transpose + dtype convert: in[bt][r][c] -> out[bt][c][r], R=1024, C=2^log2C
__global__ void t_kern(const void* __restrict__ in, unsigned short* __restrict__ out,
                       const int* __restrict__ flag, int log2C, int total) {
    int id = blockIdx.x * 256 + threadIdx.x;
    if (id >= total) return;
    unsigned short v;
    if (*flag) v = ((const unsigned short*)in)[id];
    else       v = f2b(((const float*)in)[id]);
    int c  = id & ((1 << log2C) - 1);
    int r  = (id >> log2C) & 1023;
    int bt = id >> (log2C + 10);
    out[(bt << (log2C + 10)) + (c << 10) + r] = v;
}

// Pack adj (8M int32 0/1) into a bitmask, 1 bit per element, via ballot.
__global__ void pack_adj(const int* __restrict__ adj,
                         unsigned long long* __restrict__ mask) {
    int gid = blockIdx.x * 256 + threadIdx.x;
    int lane = threadIdx.x & 63;
    unsigned long long m = __ballot(adj[gid] > 0);
    if (lane == 0) mask[gid >> 6] = m;
}

// K1: Wh = x @ W[h]  (M=8192, N=1024=H*E, K=1024), writes WhT[hb][e][m] bf16.
__global__ __launch_bounds__(256) void k1_gemm(
        const unsigned short* __restrict__ x,
        const unsigned short* __restrict__ WT,      // [H][E=256][K=1024]
        unsigned short* __restrict__ WhT) {         // [H*8+b][256][1024]
    __shared__ unsigned short smA[8 * 512];
    __shared__ unsigned short smB[8 * 512];
    int tid = threadIdx.x;
    int w = tid >> 6, lane = tid & 63;
    int lr = lane & 15, lq = lane >> 4;
    int col0 = blockIdx.x * 128;
    int row0 = blockIdx.y * 128;
    int h = col0 >> 8;
    int e_base = col0 & 255;
    int b = row0 >> 10;
    int m_base = row0 & 1023;
    int wr = w >> 1, wc = w & 1;

    f32x4 acc[4][4] = {};

    for (int k0 = 0; k0 < 1024; k0 += 32) {
        __syncthreads();
#pragma unroll
        for (int s = 0; s < 2; s++) {
            int g = 2 * w + s;
            const unsigned short* srcA =
                x + (size_t)(row0 + g * 16 + lr) * 1024 + k0 + lq * 8;
            glds16(srcA, &smA[g * 512]);
            const unsigned short* srcB =
                WT + (size_t)(h * 256 + e_base + g * 16 + lr) * 1024 + k0 + lq * 8;
            glds16(srcB, &smB[g * 512]);
        }
        __syncthreads();
        short8 af[4], bf[4];
#pragma unroll
        for (int i = 0; i < 4; i++)
            af[i] = *(const short8*)&smA[(wr * 4 + i) * 512 + lane * 8];
#pragma unroll
        for (int j = 0; j < 4; j++)
            bf[j] = *(const short8*)&smB[(wc * 4 + j) * 512 + lane * 8];
#pragma unroll
        for (int i = 0; i < 4; i++)
#pragma unroll
            for (int j = 0; j < 4; j++)
                acc[i][j] = __builtin_amdgcn_mfma_f32_16x16x32_bf16(
                    af[i], bf[j], acc[i][j], 0, 0, 0);
    }

    int hb = h * 8 + b;
#pragma unroll
    for (int i = 0; i < 4; i++) {
#pragma unroll
        for (int j = 0; j < 4; j++) {
            int e = e_base + (wc * 4 + j) * 16 + lr;
            int m = m_base + (wr * 4 + i) * 16 + lq * 4;
            ushort4 vs;
            vs.x = f2b(acc[i][j][0]);
            vs.y = f2b(acc[i][j][1]);
            vs.z = f2b(acc[i][j][2]);
            vs.w = f2b(acc[i][j][3]);
            *(ushort4*)&WhT[(size_t)(hb * 256 + e) * 1024 + m] = vs;
        }
    }
}

// K1b: f1[hb][n] = sum_e WhT[hb][e][n]*a1[h][e]; f2 likewise.
__global__ void k1b_f12(const unsigned short* __restrict__ WhT,
                        const unsigned short* __restrict__ a1,
                        const unsigned short* __restrict__ a2,
                        float* __restrict__ f1, float* __restrict__ f2) {
    int hb = blockIdx.y;
    int n = blockIdx.x * 256 + threadIdx.x;
    int h = hb >> 3;
    float s1 = 0.f, s2 = 0.f;
    for (int e = 0; e < 256; e++) {
        float wv = b2f(WhT[(size_t)(hb * 256 + e) * 1024 + n]);
        s1 += wv * b2f(a1[h * 256 + e]);
        s2 += wv * b2f(a2[h * 256 + e]);
    }
    f1[hb * 1024 + n] = s1;
    f2[hb * 1024 + n] = s2;
}

// K2: masked-softmax attention + P@Wh + ELU -> feat[bn][h*256+e] bf16.
// 4 waves/block; wave w owns rows n0+w*16..+15 and ALL 256 e (16 MFMAs/iter).
// p computed once per (hb,n,m); adj via packed bitmask; operand prefetch
// pipelined so exp/repack VALU fills the glds drain window.
__global__ __launch_bounds__(256, 4) void k2_attn(
        const unsigned short* __restrict__ WhT,
        const unsigned int* __restrict__ amask,     // [8][1024][32] u32 bit rows
        const float* __restrict__ f1, const float* __restrict__ f2,
        unsigned short* __restrict__ feat) {
    __shared__ unsigned short smW[16 * 512];        // 16 KB: 16 e-tiles x (16e x 32m)
    int tid = threadIdx.x;
    int w = tid >> 6, lane = tid & 63;
    int lr = lane & 15, lq = lane >> 4;
    int n0 = blockIdx.x * 64;
    int hb = blockIdx.y;
    int h = hb >> 3, b = hb & 7;
    int n = n0 + w * 16 + lr;
    float f1n = f1[hb * 1024 + n];
    const unsigned short* whbase = WhT + (size_t)hb * 256 * 1024;
    const unsigned int* amrow = amask + (size_t)(b * 1024 + n) * 32;
    const float* f2row = f2 + hb * 1024;

    f32x4 acc[16] = {};
    float den = 0.f;

    // prefetch iteration-0 operands
    unsigned int mw = amrow[0];
    float4 f20 = *(const float4*)(f2row + lq * 8);
    float4 f21 = *(const float4*)(f2row + lq * 8 + 4);

    for (int m0 = 0; m0 < 1024; m0 += 32) {
        __syncthreads();                 // previous iter's LDS readers done
#pragma unroll
        for (int s = 0; s < 4; s++) {
            int t = w * 4 + s;           // 16 e-tiles staged by 4 waves
            glds16(whbase + (size_t)(t * 16 + lr) * 1024 + m0 + lq * 8,
                   &smW[t * 512]);
        }
        // p-compute from prefetched operands (overlaps glds latency)
        float fm[8] = {f20.x, f20.y, f20.z, f20.w, f21.x, f21.y, f21.z, f21.w};
        short8 af;
        unsigned int mcur = mw;
#pragma unroll
        for (int j = 0; j < 8; j++) {
            float t_ = f1n + fm[j];
            float e_ = t_ > 0.f ? t_ : 0.2f * t_;                 // leaky relu
            float p  = ((mcur >> (lq * 8 + j)) & 1u) ? __expf(e_) : 0.f;
            unsigned short pb = f2b(p);
            af[j] = (short)pb;
            den += b2f(pb);              // bf16-rounded p: consistent num/denom
        }
        // prefetch next iteration's operands
        int mn = m0 + 32;
        if (mn < 1024) {
            mw  = amrow[mn >> 5];
            f20 = *(const float4*)(f2row + mn + lq * 8);
            f21 = *(const float4*)(f2row + mn + lq * 8 + 4);
        }
        __syncthreads();                 // glds data visible
#pragma unroll
        for (int i = 0; i < 16; i++) {
            short8 bf = *(const short8*)&smW[i * 512 + lane * 8];
            acc[i] = __builtin_amdgcn_mfma_f32_16x16x32_bf16(af, bf, acc[i], 0, 0, 0);
        }
    }

    // den per lane covers (row lr, m-quad lq); reduce over the 4 quads
    den += __shfl_xor(den, 16, 64);
    den += __shfl_xor(den, 32, 64);

#pragma unroll
    for (int rr = 0; rr < 4; rr++) {
        float dr = __shfl(den, lq * 4 + rr, 64);   // den of C-layout row
        float rdr = 1.0f / dr;
        int nn = n0 + w * 16 + lq * 4 + rr;
#pragma unroll
        for (int i = 0; i < 16; i++) {
            int e = i * 16 + lr;
            float v = acc[i][rr] * rdr;
            float o = v > 0.f ? v : __expf(v) - 1.f;   // elu
            feat[(size_t)(b * 1024 + nn) * 1024 + h * 256 + e] = f2b(o);
        }
    }
}

// K3: out = feat @ W_act + b_act  (M=8192, K=1024, N=64), out dtype per flag.
__global__ __launch_bounds__(256) void k3_out(
        const unsigned short* __restrict__ feat,
        const unsigned short* __restrict__ WactT,   // [64][1024]
        const unsigned short* __restrict__ bact,
        void* __restrict__ out, const int* __restrict__ flag) {
    __shared__ unsigned short smA[2 * 512];
    __shared__ unsigned short smB[4 * 512];
    int tid = threadIdx.x;
    int w = tid >> 6, lane = tid & 63;
    int lr = lane & 15, lq = lane >> 4;
    int row0 = blockIdx.x * 32;
    int g = w & 1, ch = w >> 1;
    int bf16out = *flag;
    f32x4 acc[2] = {};

    for (int k0 = 0; k0 < 1024; k0 += 32) {
        __syncthreads();
        if (w < 2) {
            const unsigned short* src =
                feat + (size_t)(row0 + w * 16 + lr) * 1024 + k0 + lq * 8;
            glds16(src, &smA[w * 512]);
        } else {
#pragma unroll
            for (int s = 0; s < 2; s++) {
                int t = (w - 2) * 2 + s;
                const unsigned short* src =
                    WactT + (size_t)(t * 16 + lr) * 1024 + k0 + lq * 8;
                glds16(src, &smB[t * 512]);
            }
        }
        __syncthreads();
        short8 af = *(const short8*)&smA[g * 512 + lane * 8];
#pragma unroll
        for (int j = 0; j < 2; j++) {
            short8 bf = *(const short8*)&smB[(ch * 2 + j) * 512 + lane * 8];
            acc[j] = __builtin_amdgcn_mfma_f32_16x16x32_bf16(af, bf, acc[j], 0, 0, 0);
        }
    }
#pragma unroll
    for (int j = 0; j < 2; j++) {
        int col = ch * 32 + j * 16 + lr;
        float bv = b2f(bact[col]);
#pragma unroll
        for (int rr = 0; rr < 4; rr++) {
            int r = row0 + g * 16 + lq * 4 + rr;
            float val = acc[j][rr] + bv;
            if (bf16out) ((unsigned short*)out)[(size_t)r * 64 + col] = f2b(val);
            else         ((float*)out)[(size_t)r * 64 + col] = val;
        }
    }
}

extern "C" void kernel_launch(void* const* d_in, const int* in_sizes, int n_in,
                              void* d_out, int out_size, void* d_ws, size_t ws_size,
                              hipStream_t stream) {
    const void* x    = d_in[0];
    const int*  adj  = (const int*)d_in[1];
    const void* W    = d_in[2];
    const void* a1   = d_in[3];
    const void* a2   = d_in[4];
    const void* Wact = d_in[5];
    const void* bact = d_in[6];

    char* ws = (char*)d_ws;
    // Workspace layout (~36.05 MB). xb aliases feat (xb dead before k2 writes
    // feat). amask aliases WT (WT dead after k1_gemm; pack_adj runs after k1).
    unsigned short* WhT   = (unsigned short*)(ws);               // 16 MB  [32][256][1024]
    unsigned short* xb    = (unsigned short*)(ws + 16777216);    // 16 MB  (== feat)
    unsigned short* feat  = (unsigned short*)(ws + 16777216);    // 16 MB  [8192][1024]
    unsigned short* WT    = (unsigned short*)(ws + 33554432);    //  2 MB  [4][256][1024]
    unsigned int*   amask = (unsigned int*)(ws + 33554432);      //  1 MB  (== WT, after k1)
    unsigned short* WactT = (unsigned short*)(ws + 35651584);    // 128 KB [64][1024]
    float*          f1    = (float*)(ws + 35782656);             // 128 KB [32][1024]
    float*          f2    = (float*)(ws + 35913728);             // 128 KB [32][1024]
    unsigned short* a1b   = (unsigned short*)(ws + 36044800);    // 2 KB
    unsigned short* a2b   = (unsigned short*)(ws + 36046848);    // 2 KB
    unsigned short* bactb = (unsigned short*)(ws + 36048896);    // 128 B
    int*            flag  = (int*)(ws + 36049024);               // 16 B
    if (ws_size < (size_t)36049040) return;

    detect_kern<<<1, 64, 0, stream>>>((const unsigned int*)x, flag);
    conv8<<<4096, 256, 0, stream>>>(x, xb, flag, 1048576);
    conv8<<<1, 256, 0, stream>>>(a1, a1b, flag, 128);
    conv8<<<1, 256, 0, stream>>>(a2, a2b, flag, 128);
    conv8<<<1, 256, 0, stream>>>(bact, bactb, flag, 8);
    t_kern<<<4096, 256, 0, stream>>>(W, WT, flag, 8, 1048576);
    t_kern<<<256, 256, 0, stream>>>(Wact, WactT, flag, 6, 65536);
    k1_gemm<<<dim3(8, 64), 256, 0, stream>>>(xb, WT, WhT);
    pack_adj<<<32768, 256, 0, stream>>>(adj, (unsigned long long*)amask);
    k1b_f12<<<dim3(4, 32), 256, 0, stream>>>(WhT, a1b, a2b, f1, f2);
    k2_attn<<<dim3(16, 32), 256, 0, stream>>>(WhT, amask, f1, f2, feat);
    k3_out<<<256, 256, 0, stream>>>(feat, WactT, bactb, d_out, flag);
}